// Round 4
// baseline (872.872 us; speedup 1.0000x reference)
//
#include <hip/hip_runtime.h>
#include <math.h>

// Problem constants (fixed by setup_inputs):
//   x: (512, 512, 9, 9) fp32, theta: (4,) fp32, lam: (4,) fp32
//   out: (4*512, 512, 9, 9) fp32 = gabor[g,h,w] * x[co,ci,h,w]
#define NG     4
#define HW     81                    // 9*9
#define NELT   (512 * 512 * 81)      // 21,233,664 floats
#define N4     (NELT / 4)            // 5,308,416 float4
#define BLK    256
#define NCHUNK (N4 / BLK)            // 20,736 chunks of 256 float4, exact
#define CSTRIDE 2048                 // chunk-stride per block group

typedef float vf4 __attribute__((ext_vector_type(4)));

// One (chunk-lane, g) pair per block: blockIdx.x = c*4 + g.
// Each block has exactly ONE linear read stream (x slice) and ONE linear
// write stream (out[g] slice) -- structurally matching the harness fill
// kernel that sustains 6.3 TB/s, instead of 1 read + 4 write streams
// interleaved per wave. The 4 sibling blocks (same c, g=0..3) are
// dispatch-adjacent so they stream the SAME x addresses concurrently:
// x (84.9 MB) is L3-resident, so ~3 of 4 reads are L3 hits.
__global__ __launch_bounds__(BLK) void gabor_mul_kernel(
    const float* __restrict__ x,
    const float* __restrict__ theta,
    const float* __restrict__ lam,
    float* __restrict__ out)
{
    __shared__ float gr[HW];         // this block's single gabor row

    const int g = (int)(blockIdx.x & 3u);
    const unsigned c = blockIdx.x >> 2;

    const float PI_F = 3.14159274101257324f;              // np.float32(np.pi)
    const float INV_2SIG2 = 1.0f / (2.0f * PI_F * PI_F);  // sigma = pi
    if (threadIdx.x < HW) {
        int p = threadIdx.x;
        int i = p / 9;
        int j = p - i * 9;
        float fy = (float)(i - 4);
        float fx = (float)(j - 4);
        // env is rotation-invariant: xr^2 + yr^2 = fx^2 + fy^2
        float env = expf(-(fx * fx + fy * fy) * INV_2SIG2);
        float th = theta[g];
        float l  = lam[g];
        float xr = fx * cosf(th) + fy * sinf(th);
        gr[p] = env * cosf(2.0f * PI_F * xr * l);
    }
    __syncthreads();

    const vf4* __restrict__ x4 = (const vf4*)x;
    vf4* __restrict__ o4 = (vf4*)out + (size_t)g * N4;

    for (unsigned i = c; i < NCHUNK; i += CSTRIDE) {
        unsigned f = i * BLK + threadIdx.x;     // float4 index, wave-contiguous

        vf4 xv = x4[f];

        unsigned p0 = (f * 4u) % 81u;           // magic-mul, no div unit
        unsigned p1 = p0 + 1u; if (p1 >= 81u) p1 -= 81u;
        unsigned p2 = p1 + 1u; if (p2 >= 81u) p2 -= 81u;
        unsigned p3 = p2 + 1u; if (p3 >= 81u) p3 -= 81u;

        vf4 o = { xv.x * gr[p0], xv.y * gr[p1], xv.z * gr[p2], xv.w * gr[p3] };

        o4[f] = o;                              // single linear write stream
    }
}

extern "C" void kernel_launch(void* const* d_in, const int* in_sizes, int n_in,
                              void* d_out, int out_size, void* d_ws, size_t ws_size,
                              hipStream_t stream) {
    const float* x     = (const float*)d_in[0];
    const float* theta = (const float*)d_in[1];
    const float* lam   = (const float*)d_in[2];
    float* out = (float*)d_out;

    gabor_mul_kernel<<<NCHUNK / CSTRIDE * NG * CSTRIDE / 1, BLK, 0, stream>>>(x, theta, lam, out);
    // grid = 4 * 2048 = 8192 blocks: (c, g) pairs, c in [0,2048), g in [0,4)
}

// Round 5
// 418.319 us; speedup vs baseline: 2.0866x; 2.0866x over previous
//
#include <hip/hip_runtime.h>
#include <math.h>

// Problem constants (fixed by setup_inputs):
//   x: (512, 512, 9, 9) fp32, theta: (4,) fp32, lam: (4,) fp32
//   out: (4*512, 512, 9, 9) fp32 = gabor[g,h,w] * x[co,ci,h,w]
#define NG      4
#define HW      81                   // 9*9
#define NELT    (512 * 512 * 81)     // 21,233,664 floats
#define N4      (NELT / 4)           // 5,308,416 float4
#define BLK     256
#define NCHUNK  (N4 / BLK)           // 20,736 chunks of 256 float4, exact
// Chunk stride 2025 = 81*25: element stride per iteration = 2025*256*4 ≡ 0 (mod 81),
// so each thread's 4 gabor positions are LOOP-INVARIANT -> registers, no LDS.
#define CSTRIDE 2025
#define GRID    (NG * CSTRIDE)       // 8100 blocks

typedef float vf4 __attribute__((ext_vector_type(4)));

// g is the SLOW block index: blockIdx = g*2025 + c. All ~2048 co-resident
// blocks belong to one g-tranche, so chip-wide there is ONE dense linear
// read frontier (x) and ONE dense linear write frontier (out[g]) -- the
// structure the harness fill kernel sustains 6.4 TB/s with. Round 4's
// g-fast layout pinned one g per XCD (blockIdx%8 round-robin!) and made
// every XCD stream all of x through its private L2: 2.83 GB HBM traffic.
__global__ __launch_bounds__(BLK) void gabor_mul_kernel(
    const float* __restrict__ x,
    const float* __restrict__ theta,
    const float* __restrict__ lam,
    float* __restrict__ out)
{
    const unsigned b = blockIdx.x;
    const unsigned g = b / CSTRIDE;          // slow index: whole tranche per g
    const unsigned c = b - g * CSTRIDE;

    const float PI_F = 3.14159274101257324f;              // np.float32(np.pi)
    const float INV_2SIG2 = 1.0f / (2.0f * PI_F * PI_F);  // sigma = pi
    const float th = theta[g];
    const float l  = lam[g];
    const float cs = cosf(th);
    const float sn = sinf(th);

    // This thread's 4 loop-invariant gabor coefficients (positions e0..e0+3 mod 81).
    const unsigned f0 = c * BLK + threadIdx.x;   // first float4 index
    const unsigned e0 = (f0 * 4u) % 81u;         // magic-mul, no div unit
    float r0, r1, r2, r3;
#pragma unroll
    for (int k = 0; k < 4; ++k) {
        unsigned p = e0 + (unsigned)k; if (p >= 81u) p -= 81u;
        int i = (int)(p / 9u);
        int j = (int)p - 9 * i;
        float fy = (float)(i - 4);
        float fx = (float)(j - 4);
        // env is rotation-invariant: xr^2 + yr^2 = fx^2 + fy^2
        float env = expf(-(fx * fx + fy * fy) * INV_2SIG2);
        float xr  = fx * cs + fy * sn;
        float v   = env * cosf(2.0f * PI_F * xr * l);
        if (k == 0) r0 = v; else if (k == 1) r1 = v; else if (k == 2) r2 = v; else r3 = v;
    }

    const vf4* __restrict__ x4 = (const vf4*)x;
    vf4* __restrict__ o4 = (vf4*)out + (size_t)g * N4;

    // Hot loop: load dwordx4, 4 v_mul_f32, store dwordx4. No LDS, no barrier.
    for (unsigned i = c; i < NCHUNK; i += CSTRIDE) {
        unsigned f = i * BLK + threadIdx.x;      // wave-contiguous float4 index
        vf4 xv = x4[f];
        vf4 o  = { xv.x * r0, xv.y * r1, xv.z * r2, xv.w * r3 };
        o4[f] = o;
    }
}

extern "C" void kernel_launch(void* const* d_in, const int* in_sizes, int n_in,
                              void* d_out, int out_size, void* d_ws, size_t ws_size,
                              hipStream_t stream) {
    const float* x     = (const float*)d_in[0];
    const float* theta = (const float*)d_in[1];
    const float* lam   = (const float*)d_in[2];
    float* out = (float*)d_out;

    gabor_mul_kernel<<<GRID, BLK, 0, stream>>>(x, theta, lam, out);
}